// Round 12
// baseline (206.087 us; speedup 1.0000x reference)
//
#include <hip/hip_runtime.h>
#include <hip/hip_fp16.h>

#define DFEAT 64
#define NG 64
#define TILE 128        // nodes per bucket/tile (bucket = tgt >> 7)
#define NBLK 256        // binning blocks
#define NBMAX 1024      // max buckets supported in LDS
#define NREP 16         // replicated accumulators for T pooling
#define SENT 0x7FFFFFFF // order[] sentinel for invalid slots
#define CAP 2048        // fixed region capacity per bucket (fits padded worst case)

typedef int v4i __attribute__((ext_vector_type(4)));
__device__ __forceinline__ int4 ntload4(const int* p) {
  v4i v = __builtin_nontemporal_load((const v4i*)p);
  return make_int4(v.x, v.y, v.z, v.w);
}

// ---- fused binning: LDS histogram -> global bucket cursors -> place; ----------
// ---- block NBLK instead zeroes S/Tr and computes WW=W1@W2, bw, counts ----------
__global__ __launch_bounds__(256) void k_binfuse(const int* __restrict__ row,
                                                 const int* __restrict__ col,
                                                 int* __restrict__ gcur,
                                                 int* __restrict__ pairs,
                                                 const float* __restrict__ W1,
                                                 const float* __restrict__ W2,
                                                 const float* __restrict__ b1,
                                                 const int* __restrict__ batch,
                                                 float* __restrict__ WW,
                                                 float* __restrict__ bw,
                                                 float* __restrict__ cntf,
                                                 float* __restrict__ S,
                                                 float* __restrict__ Tr,
                                                 int e, int nb, int chunk, int n) {
  __shared__ int shm[8192];  // 32 KB dual-use
  int tid = threadIdx.x;
  int blk = blockIdx.x;
  if (blk == NBLK) {  // zero accumulators + weight pre-multiply + graph counts
    for (int i = tid; i < NG * DFEAT; i += 256) S[i] = 0.f;
    for (int i = tid; i < NREP * NG; i += 256) Tr[i] = 0.f;
    float* w1 = (float*)shm;
    float* w2 = (float*)shm + 4096;
    for (int i = tid; i < 4096; i += 256) { w1[i] = W1[i]; w2[i] = W2[i]; }
    if (tid < NG) {
      int g = tid;
      int lo = 0, hi = n;
      while (lo < hi) { int m = (lo + hi) >> 1; if (batch[m] < g) lo = m + 1; else hi = m; }
      int a = lo;
      lo = 0; hi = n;
      while (lo < hi) { int m = (lo + hi) >> 1; if (batch[m] < g + 1) lo = m + 1; else hi = m; }
      cntf[g] = (float)(lo - a);
    }
    __syncthreads();
    for (int p = tid; p < 4096; p += 256) {
      int k = p >> 6, d = p & 63;
      float a = 0.f;
      for (int m = 0; m < 64; ++m) a += w1[k * 64 + m] * w2[m * 64 + d];
      WW[p] = a;
    }
    if (tid < 64) {
      float a = 0.f;
      for (int k = 0; k < 64; ++k) a += b1[k] * w2[k * 64 + tid];
      bw[tid] = a;
    }
    return;
  }
  int* hist = shm;          // histogram, then local cursor
  int* gl = shm + NBMAX;    // this block's global base per bucket
  for (int b = tid; b < nb; b += 256) hist[b] = 0;
  __syncthreads();
  int lo = blk * chunk, hi = min(lo + chunk, e);  // lo 4-aligned (chunk%4==0)
  if (lo < hi) {
    int nv = (hi - lo) >> 2;
    const int4* c4 = (const int4*)(col + lo);
    for (int i = tid; i < nv; i += 256) {
      int4 v = c4[i];
      atomicAdd(&hist[v.x >> 7], 1);
      atomicAdd(&hist[v.y >> 7], 1);
      atomicAdd(&hist[v.z >> 7], 1);
      atomicAdd(&hist[v.w >> 7], 1);
    }
    for (int i = lo + (nv << 2) + tid; i < hi; i += 256)
      atomicAdd(&hist[col[i] >> 7], 1);
  }
  __syncthreads();
  // reserve a contiguous range inside each bucket's fixed region
  for (int b = tid; b < nb; b += 256) {
    int h = hist[b];
    gl[b] = (h > 0) ? (b * CAP + atomicAdd(&gcur[b], h)) : 0;
    hist[b] = 0;  // becomes local cursor
  }
  __syncthreads();
  if (lo < hi) {  // placement pass: last touch of the edge list -> non-temporal
    int nv = (hi - lo) >> 2;
    const int4* r4 = (const int4*)(row + lo);
    const int4* c4 = (const int4*)(col + lo);
    for (int i = tid; i < nv; i += 256) {
      int4 rs = ntload4((const int*)(r4 + i));
      int4 ts = ntload4((const int*)(c4 + i));
#pragma unroll
      for (int k = 0; k < 4; ++k) {
        int s = (&rs.x)[k], t = (&ts.x)[k];
        int b = t >> 7;
        int pos = gl[b] + atomicAdd(&hist[b], 1);
        pairs[pos] = s | ((t & (TILE - 1)) << 20);
      }
    }
    for (int i = lo + (nv << 2) + tid; i < hi; i += 256) {
      int s = __builtin_nontemporal_load(row + i);
      int t = __builtin_nontemporal_load(col + i);
      int b = t >> 7;
      int pos = gl[b] + atomicAdd(&hist[b], 1);
      pairs[pos] = s | ((t & (TILE - 1)) << 20);
    }
  }
}

// ------- per-tile CSR (4-padded per-node segments) + xs conv + degree sort -----
// starts2[node] = srcs_pos | (deg << 22); node's segment is 4-aligned and padded
// to a multiple of 4 with REPLICATED LAST SRC (so gathers need no clamping).
__global__ __launch_bounds__(256) void k_csr(const int* __restrict__ pairs,
                                             const int* __restrict__ gcur,
                                             const float* __restrict__ x,
                                             int* __restrict__ starts2,
                                             int* __restrict__ srcs,
                                             float* __restrict__ dinv,
                                             __half2* __restrict__ xh,
                                             int* __restrict__ order,
                                             int n) {
  __shared__ int cnt[TILE];
  __shared__ int cur[TILE];
  __shared__ int sc[TILE];
  __shared__ float sdv[TILE];
  __shared__ int dh[64], dcur[64];
  int tid = threadIdx.x;
  int b = blockIdx.x;
  int tile0 = b * TILE;
  if (tid < TILE) cnt[tid] = 0;
  if (tid >= TILE && tid < TILE + 64) dh[tid - TILE] = 0;
  __syncthreads();
  int e0 = b * CAP, e1 = e0 + gcur[b];
  for (int i = e0 + tid; i < e1; i += 256)
    atomicAdd(&cnt[(unsigned)pairs[i] >> 20], 1);
  __syncthreads();
  int c = (tid < TILE) ? cnt[tid] : 0;
  int cp = (c + 3) & ~3;  // padded segment size (0 stays 0)
  if (tid < TILE) sc[tid] = cp;
  __syncthreads();
  for (int off = 1; off < TILE; off <<= 1) {
    int t = (tid < TILE && tid >= off) ? sc[tid - off] : 0;
    __syncthreads();
    if (tid < TILE) sc[tid] += t;
    __syncthreads();
  }
  int mybin = 63;
  if (tid < TILE) {
    int excl = sc[tid] - cp;
    cur[tid] = excl;
    int node = tile0 + tid;
    float d = rsqrtf(1.0f + (float)c);
    sdv[tid] = (node < n) ? d : 0.f;
    if (node < n) {
      starts2[node] = (e0 + excl) | (c << 22);
      dinv[node] = d;
      mybin = min(c, 62);  // valid nodes sort before invalid (bin 63)
    }
    atomicAdd(&dh[mybin], 1);
  }
  __syncthreads();
  if (tid == 0) {  // exclusive scan of 64 degree bins
    int a = 0;
    for (int i = 0; i < 64; ++i) { int t = dh[i]; dcur[i] = a; a += t; }
  }
  __syncthreads();
  if (tid < TILE) {
    int rank = atomicAdd(&dcur[mybin], 1);
    int node = tile0 + tid;
    order[tile0 + rank] = (node < n) ? node : SENT;
  }
  // edge placement (node-ordered within tile)
  for (int i = e0 + tid; i < e1; i += 256) {
    int p = pairs[i];
    int pos = atomicAdd(&cur[(unsigned)p >> 20], 1);
    srcs[e0 + pos] = p & 0xFFFFF;
  }
  __syncthreads();
  // pad fill: replicate last src into the pad slots (clamp baked into data)
  if (tid < TILE && c > 0) {
    int base = e0 + sc[tid] - cp;
    int last = srcs[base + c - 1];
    for (int q = c; q < cp; ++q) srcs[base + q] = last;
  }
  // fused conversion: xs = dinv[node] * x (fp16)
  int nnode = min(n - tile0, TILE);
  if (nnode > 0) {
    int nfl = nnode * 16;  // float4 units
    const float4* xf = (const float4*)(x + (size_t)tile0 * 64);
    float2* xo = (float2*)xh + (size_t)tile0 * 16;
    for (int p = tid; p < nfl; p += 256) {
      float4 v = xf[p];
      float d = sdv[p >> 4];
      float2 st;
      ((__half2*)&st)[0] = __floats2half2_rn(v.x * d, v.y * d);
      ((__half2*)&st)[1] = __floats2half2_rn(v.z * d, v.w * d);
      xo[p] = st;
    }
  }
}

// --------- weighted accumulate: 8 halves of a float4-of-half2, w in {0,1} ------
__device__ __forceinline__ void acc8w(float2& a0, float2& a1, float2& a2,
                                      float2& a3, float4 v, float w) {
  const __half2* hp = (const __half2*)&v;
  float2 t;
  t = __half22float2(hp[0]); a0.x = fmaf(w, t.x, a0.x); a0.y = fmaf(w, t.y, a0.y);
  t = __half22float2(hp[1]); a1.x = fmaf(w, t.x, a1.x); a1.y = fmaf(w, t.y, a1.y);
  t = __half22float2(hp[2]); a2.x = fmaf(w, t.x, a2.x); a2.y = fmaf(w, t.y, a2.y);
  t = __half22float2(hp[3]); a3.x = fmaf(w, t.x, a3.x); a3.y = fmaf(w, t.y, a3.y);
}
__device__ __forceinline__ void acc8(float2& a0, float2& a1, float2& a2,
                                     float2& a3, float4 v) {
  const __half2* hp = (const __half2*)&v;
  float2 t;
  t = __half22float2(hp[0]); a0.x += t.x; a0.y += t.y;
  t = __half22float2(hp[1]); a1.x += t.x; a1.y += t.y;
  t = __half22float2(hp[2]); a2.x += t.x; a2.y += t.y;
  t = __half22float2(hp[3]); a3.x += t.x; a3.y += t.y;
}

// ------- gather1: z1s = dc^2*(xs_self + sum xs[srcs]); u-pool into Tr ----------
// Padded srcs: one NON-TEMPORAL int4 index load per trip (stream; protect L2
// for the 12.8 MB row working set), no clamp chains.
__global__ __launch_bounds__(256) void k_gather1(const int* __restrict__ starts2,
                                                 const int* __restrict__ srcs,
                                                 const float* __restrict__ dinv,
                                                 const __half2* __restrict__ xh,
                                                 const int* __restrict__ batch,
                                                 const int* __restrict__ order,
                                                 __half2* __restrict__ z1h,
                                                 float* __restrict__ Tr, int n) {
  int tid = threadIdx.x;
  int slot = blockIdx.x * 32 + (tid >> 3);
  int node = order[slot];
  bool act = node < n;
  int nc = act ? node : n - 1;
  int l = tid & 7;
  int lane = tid & 63;
  int rep = blockIdx.x & (NREP - 1);
  unsigned sv2 = (unsigned)starts2[nc];
  int s = sv2 & 0x3FFFFF;
  int deg = act ? (int)(sv2 >> 22) : 0;
  float dc = dinv[nc];
  int g = batch[nc];
  const float4* xf = (const float4*)xh;
  float4 sv = xf[(size_t)nc * 8 + l];
  float2 a0 = make_float2(0.f, 0.f), a1 = a0, a2 = a0, a3 = a0;
  acc8(a0, a1, a2, a3, sv);  // self term
  float wsum = 0.f;
  int trips = (deg + 3) >> 2;
  const int* sp = srcs + s;
  int4 nx = (trips > 0) ? ntload4(sp) : make_int4(0, 0, 0, 0);
  int j = 0;
  int tl = trips - 1;
  for (int t = 0; t < trips; ++t) {
    int4 cu = nx;
    nx = ntload4(sp + 4 * min(t + 1, tl));
    float w1w = (j + 1 < deg) ? 1.f : 0.f;
    float w2w = (j + 2 < deg) ? 1.f : 0.f;
    float w3w = (j + 3 < deg) ? 1.f : 0.f;
    float4 v0 = xf[(size_t)cu.x * 8 + l];
    float4 v1 = xf[(size_t)cu.y * 8 + l];
    float4 v2 = xf[(size_t)cu.z * 8 + l];
    float4 v3 = xf[(size_t)cu.w * 8 + l];
    wsum += dinv[cu.x] + w1w * dinv[cu.y] + w2w * dinv[cu.z] + w3w * dinv[cu.w];
    acc8(a0, a1, a2, a3, v0);
    acc8w(a0, a1, a2, a3, v1, w1w);
    acc8w(a0, a1, a2, a3, v2, w2w);
    acc8w(a0, a1, a2, a3, v3, w3w);
    j += 4;
  }
  if (act) {
    float s2 = dc * dc;
    float4 ov;
    __half2* op = (__half2*)&ov;
    op[0] = __floats2half2_rn(s2 * a0.x, s2 * a0.y);
    op[1] = __floats2half2_rn(s2 * a1.x, s2 * a1.y);
    op[2] = __floats2half2_rn(s2 * a2.x, s2 * a2.y);
    op[3] = __floats2half2_rn(s2 * a3.x, s2 * a3.y);
    ((float4*)z1h)[(size_t)node * 8 + l] = ov;
  }
  // pool u = dc*(dc+wsum) into T_rep (one atomic per wave in the common case)
  float uval = act ? dc * (dc + wsum) : 0.f;
  int g0 = __shfl(g, 0);
  bool uni = (__all(g == g0) != 0);
  if (!uni) {
    if (act && l == 0) unsafeAtomicAdd(&Tr[rep * NG + g], uval);
  } else {
    float uv = (l == 0) ? uval : 0.f;
    uv += __shfl_xor(uv, 8);
    uv += __shfl_xor(uv, 16);
    uv += __shfl_xor(uv, 32);
    if (lane == 0 && uv != 0.f) unsafeAtomicAdd(&Tr[rep * NG + g0], uv);
  }
}

// ------- gather2: row = dc*(z1s_self + sum z1s[srcs]); LDS-pool -> Pb partials --
__global__ __launch_bounds__(256) void k_gather2(const int* __restrict__ starts2,
                                                 const int* __restrict__ srcs,
                                                 const float* __restrict__ dinv,
                                                 const __half2* __restrict__ z1h,
                                                 const int* __restrict__ batch,
                                                 const int* __restrict__ order,
                                                 float* __restrict__ Pb,
                                                 float* __restrict__ S, int n) {
  __shared__ float rowacc[2][64];
  __shared__ int sgid[2];
  int tid = threadIdx.x;
  int blk0 = (int)blockIdx.x * 32;
  int slot = blk0 + (tid >> 3);
  int node = order[slot];
  bool act = node < n;
  int nc = act ? node : n - 1;
  int l = tid & 7;
  int lane = tid & 63;
  unsigned sv2 = (unsigned)starts2[nc];
  int s = sv2 & 0x3FFFFF;
  int deg = act ? (int)(sv2 >> 22) : 0;
  float dc = dinv[nc];
  int g = batch[nc];
  if (tid < 128) ((float*)rowacc)[tid] = 0.f;
  if (tid < 2) {
    int tile0b = blk0 & ~(TILE - 1);
    int idx = tile0b + (tid ? (TILE - 1) : 0);
    if (idx > n - 1) idx = n - 1;
    sgid[tid] = batch[idx];
  }
  const float4* xf = (const float4*)z1h;
  float4 sv = xf[(size_t)nc * 8 + l];
  float2 a0 = make_float2(0.f, 0.f), a1 = a0, a2 = a0, a3 = a0;
  acc8(a0, a1, a2, a3, sv);  // self term
  int trips = (deg + 3) >> 2;
  const int* sp = srcs + s;
  int4 nx = (trips > 0) ? ntload4(sp) : make_int4(0, 0, 0, 0);
  int j = 0;
  int tl = trips - 1;
  for (int t = 0; t < trips; ++t) {
    int4 cu = nx;
    nx = ntload4(sp + 4 * min(t + 1, tl));
    float w1w = (j + 1 < deg) ? 1.f : 0.f;
    float w2w = (j + 2 < deg) ? 1.f : 0.f;
    float w3w = (j + 3 < deg) ? 1.f : 0.f;
    float4 v0 = xf[(size_t)cu.x * 8 + l];
    float4 v1 = xf[(size_t)cu.y * 8 + l];
    float4 v2 = xf[(size_t)cu.z * 8 + l];
    float4 v3 = xf[(size_t)cu.w * 8 + l];
    acc8(a0, a1, a2, a3, v0);
    acc8w(a0, a1, a2, a3, v1, w1w);
    acc8w(a0, a1, a2, a3, v2, w2w);
    acc8w(a0, a1, a2, a3, v3, w3w);
    j += 4;
  }
  float f[8];
  f[0] = act ? dc * a0.x : 0.f;
  f[1] = act ? dc * a0.y : 0.f;
  f[2] = act ? dc * a1.x : 0.f;
  f[3] = act ? dc * a1.y : 0.f;
  f[4] = act ? dc * a2.x : 0.f;
  f[5] = act ? dc * a2.y : 0.f;
  f[6] = act ? dc * a3.x : 0.f;
  f[7] = act ? dc * a3.y : 0.f;
  __syncthreads();
  int g_lo = sgid[0], g_hi = sgid[1];
  int sel = (g == g_lo) ? 0 : ((g == g_hi) ? 1 : -1);
  if (sel < 0 && act) {  // >2 graphs in a 128-node tile: rare
#pragma unroll
    for (int k = 0; k < 8; ++k)
      unsafeAtomicAdd(&S[g * 64 + l * 8 + k], f[k]);
  }
  float fa[8], fb[8];
#pragma unroll
  for (int k = 0; k < 8; ++k) {
    fa[k] = (sel == 0) ? f[k] : 0.f;
    fb[k] = (sel == 1) ? f[k] : 0.f;
  }
#pragma unroll
  for (int k = 0; k < 8; ++k) {  // reduce over node dim (lane bits 3..5)
    fa[k] += __shfl_xor(fa[k], 8);
    fa[k] += __shfl_xor(fa[k], 16);
    fa[k] += __shfl_xor(fa[k], 32);
    fb[k] += __shfl_xor(fb[k], 8);
    fb[k] += __shfl_xor(fb[k], 16);
    fb[k] += __shfl_xor(fb[k], 32);
  }
  if (lane < 8) {
#pragma unroll
    for (int k = 0; k < 8; ++k) {
      if (fa[k] != 0.f) atomicAdd(&rowacc[0][lane * 8 + k], fa[k]);
      if (fb[k] != 0.f) atomicAdd(&rowacc[1][lane * 8 + k], fb[k]);
    }
  }
  __syncthreads();
  float* pb = Pb + (size_t)blockIdx.x * 130;
  if (tid < 128) pb[tid] = ((float*)rowacc)[tid];
  if (tid == 128) pb[128] = (float)g_lo;
  if (tid == 129) pb[129] = (float)g_hi;
}

// ------- fused: reduce Pb partials for graph g, then out[g] directly ------------
__global__ __launch_bounds__(256) void k_fin(const float* __restrict__ Pb,
                                             const int* __restrict__ batch,
                                             const float* __restrict__ S,
                                             const float* __restrict__ Tr,
                                             const float* __restrict__ cntf,
                                             const float* __restrict__ WW,
                                             const float* __restrict__ bw,
                                             const float* __restrict__ b2,
                                             float* __restrict__ out, int n,
                                             int nbw) {
  __shared__ float sh[4][64];
  __shared__ float sG[64];
  int g = blockIdx.x;
  int d = threadIdx.x & 63, r = threadIdx.x >> 6;
  int lo = 0, hi = n;
  while (lo < hi) { int m = (lo + hi) >> 1; if (batch[m] < g) lo = m + 1; else hi = m; }
  int a = lo;
  lo = 0; hi = n;
  while (lo < hi) { int m = (lo + hi) >> 1; if (batch[m] < g + 1) lo = m + 1; else hi = m; }
  int b = lo;
  float acc = 0.f;
  if (b > a) {
    // graph g's nodes live in tiles [a>>7, (b-1)>>7]; 4 gather blocks per tile
    int bl0 = (a >> 7) << 2;
    int bl1 = min((((b - 1) >> 7) << 2) + 3, nbw - 1);
    for (int bl = bl0 + r; bl <= bl1; bl += 4) {
      const float* p = Pb + (size_t)bl * 130;
      if ((int)p[128] == g) acc += p[d];
      if ((int)p[129] == g) acc += p[64 + d];
    }
  }
  sh[r][d] = acc;
  __syncthreads();
  if (r == 0) sG[d] = acc + sh[1][d] + sh[2][d] + sh[3][d] + S[g * 64 + d];
  __syncthreads();
  if (threadIdx.x < 64) {
    float aa = 0.f;
    for (int k = 0; k < 64; ++k) aa += sG[k] * WW[k * 64 + d];
    float T = 0.f;
    for (int rr = 0; rr < NREP; ++rr) T += Tr[rr * NG + g];
    float c = fmaxf(cntf[g], 1.0f);
    out[g * 64 + d] = (aa + T * bw[d]) / c + b2[d];
  }
}

extern "C" void kernel_launch(void* const* d_in, const int* in_sizes, int n_in,
                              void* d_out, int out_size, void* d_ws, size_t ws_size,
                              hipStream_t stream) {
  const float* x = (const float*)d_in[0];
  const int* ei = (const int*)d_in[1];
  const int* bat = (const int*)d_in[2];
  const float* W1 = (const float*)d_in[3];
  const float* b1 = (const float*)d_in[4];
  const float* W2 = (const float*)d_in[5];
  const float* b2 = (const float*)d_in[6];
  float* out = (float*)d_out;

  int n = in_sizes[0] / 64;  // 100000
  int e = in_sizes[1] / 2;   // 1000000
  const int* rowp = ei;      // sources
  const int* colp = ei + e;  // targets
  int nb = (n + TILE - 1) / TILE;                  // 782 buckets (< NBMAX)
  int chunk = (((e + NBLK - 1) / NBLK) + 3) & ~3;  // 4-aligned for int4 reads
  int nbw = (n + 31) / 32;                         // gather blocks: 32 slots each

  char* ws = (char*)d_ws;
  size_t off = 0;
  auto alloc = [&](size_t elems) {
    void* p = ws + off;
    off += ((elems * 4 + 255) & ~(size_t)255);
    return p;
  };
  // zeroed prefix: gcur only (S/Tr zeroed in k_binfuse block NBLK; cntf fully
  // overwritten there)
  int* gcur = (int*)alloc(nb);
  size_t zbytes = off;
  float* S = (float*)alloc(NG * DFEAT);
  float* Tr = (float*)alloc(NREP * NG);
  float* cntf = (float*)alloc(NG);
  float* dinv = (float*)alloc(n);
  int* starts2 = (int*)alloc(n);
  int* srcs = (int*)alloc((size_t)nb * CAP);
  float* WW = (float*)alloc(DFEAT * DFEAT);
  float* bw = (float*)alloc(DFEAT);
  __half2* xh = (__half2*)alloc((size_t)n * 32);   // n*64 halves (premultiplied)
  __half2* z1h = (__half2*)alloc((size_t)n * 32);  // n*64 halves (z1s)
  int* pairs = (int*)alloc((size_t)nb * CAP);
  float* Pb = (float*)alloc((size_t)nbw * 130);    // per-block pooled partials
  int* order = (int*)alloc((size_t)nb * TILE);     // degree-sorted slot->node

  (void)hipMemsetAsync(gcur, 0, zbytes, stream);
  // fused: histogram + bucket-region reservation + placement (+W12/zero block)
  k_binfuse<<<NBLK + 1, 256, 0, stream>>>(rowp, colp, gcur, pairs, W1, W2, b1,
                                          bat, WW, bw, cntf, S, Tr, e, nb,
                                          chunk, n);
  k_csr<<<nb, 256, 0, stream>>>(pairs, gcur, x, starts2, srcs, dinv, xh, order,
                                n);

  // layer 1: z1s = dinv^2*(xs_self + sum xs) (+ fused u-pool into Tr)
  // layer 2: pooled rows -> per-block partials Pb (+ rare fallback atomics to S)
  k_gather1<<<nbw, 256, 0, stream>>>(starts2, srcs, dinv, xh, bat, order, z1h,
                                     Tr, n);
  k_gather2<<<nbw, 256, 0, stream>>>(starts2, srcs, dinv, z1h, bat, order, Pb,
                                     S, n);

  // fused partial-reduce + tiny matmul + bias
  k_fin<<<NG, 256, 0, stream>>>(Pb, bat, S, Tr, cntf, WW, bw, b2, out, n, nbw);
}

// Round 13
// 194.188 us; speedup vs baseline: 1.0613x; 1.0613x over previous
//
#include <hip/hip_runtime.h>
#include <hip/hip_fp16.h>

#define DFEAT 64
#define NG 64
#define TILE 128        // nodes per bucket/tile (bucket = tgt >> 7)
#define NBLK 256        // binning blocks
#define NBMAX 1024      // max buckets supported in LDS
#define NREP 16         // replicated accumulators for T pooling
#define SENT 0x7FFFFFFF // order[] sentinel for invalid slots
#define CAP 2048        // fixed region capacity per bucket (>20 sigma of 1280)

// ---- fused binning: LDS histogram -> global bucket cursors -> place; ----------
// ---- block NBLK instead computes WW=W1@W2, bw=b1@W2, per-graph counts ----------
__global__ __launch_bounds__(256) void k_binfuse(const int* __restrict__ row,
                                                 const int* __restrict__ col,
                                                 int* __restrict__ gcur,
                                                 int* __restrict__ pairs,
                                                 const float* __restrict__ W1,
                                                 const float* __restrict__ W2,
                                                 const float* __restrict__ b1,
                                                 const int* __restrict__ batch,
                                                 float* __restrict__ WW,
                                                 float* __restrict__ bw,
                                                 float* __restrict__ cntf,
                                                 int e, int nb, int chunk, int n) {
  __shared__ int shm[8192];  // 32 KB dual-use
  int tid = threadIdx.x;
  int blk = blockIdx.x;
  if (blk == NBLK) {  // weight pre-multiply + per-graph node counts
    float* w1 = (float*)shm;
    float* w2 = (float*)shm + 4096;
    for (int i = tid; i < 4096; i += 256) { w1[i] = W1[i]; w2[i] = W2[i]; }
    if (tid < NG) {
      int g = tid;
      int lo = 0, hi = n;
      while (lo < hi) { int m = (lo + hi) >> 1; if (batch[m] < g) lo = m + 1; else hi = m; }
      int a = lo;
      lo = 0; hi = n;
      while (lo < hi) { int m = (lo + hi) >> 1; if (batch[m] < g + 1) lo = m + 1; else hi = m; }
      cntf[g] = (float)(lo - a);
    }
    __syncthreads();
    for (int p = tid; p < 4096; p += 256) {
      int k = p >> 6, d = p & 63;
      float a = 0.f;
      for (int m = 0; m < 64; ++m) a += w1[k * 64 + m] * w2[m * 64 + d];
      WW[p] = a;
    }
    if (tid < 64) {
      float a = 0.f;
      for (int k = 0; k < 64; ++k) a += b1[k] * w2[k * 64 + tid];
      bw[tid] = a;
    }
    return;
  }
  int* hist = shm;          // histogram, then local cursor
  int* gl = shm + NBMAX;    // this block's global base per bucket
  for (int b = tid; b < nb; b += 256) hist[b] = 0;
  __syncthreads();
  int lo = blk * chunk, hi = min(lo + chunk, e);  // lo 4-aligned (chunk%4==0)
  if (lo < hi) {
    int nv = (hi - lo) >> 2;
    const int4* c4 = (const int4*)(col + lo);
    for (int i = tid; i < nv; i += 256) {
      int4 v = c4[i];
      atomicAdd(&hist[v.x >> 7], 1);
      atomicAdd(&hist[v.y >> 7], 1);
      atomicAdd(&hist[v.z >> 7], 1);
      atomicAdd(&hist[v.w >> 7], 1);
    }
    for (int i = lo + (nv << 2) + tid; i < hi; i += 256)
      atomicAdd(&hist[col[i] >> 7], 1);
  }
  __syncthreads();
  // reserve a contiguous range inside each bucket's fixed region
  for (int b = tid; b < nb; b += 256) {
    int h = hist[b];
    gl[b] = (h > 0) ? (b * CAP + atomicAdd(&gcur[b], h)) : 0;
    hist[b] = 0;  // becomes local cursor
  }
  __syncthreads();
  if (lo < hi) {
    int nv = (hi - lo) >> 2;
    const int4* r4 = (const int4*)(row + lo);
    const int4* c4 = (const int4*)(col + lo);
    for (int i = tid; i < nv; i += 256) {
      int4 rs = r4[i];
      int4 ts = c4[i];
#pragma unroll
      for (int k = 0; k < 4; ++k) {
        int s = (&rs.x)[k], t = (&ts.x)[k];
        int b = t >> 7;
        int pos = gl[b] + atomicAdd(&hist[b], 1);
        pairs[pos] = s | ((t & (TILE - 1)) << 20);
      }
    }
    for (int i = lo + (nv << 2) + tid; i < hi; i += 256) {
      int s = row[i], t = col[i];
      int b = t >> 7;
      int pos = gl[b] + atomicAdd(&hist[b], 1);
      pairs[pos] = s | ((t & (TILE - 1)) << 20);
    }
  }
}

// ------- per-tile CSR + fused xs conversion + intra-tile degree sort -----------
// starts2[node] = srcs_pos | (deg << 22)   (pos < 1.6M < 2^22, deg < 512)
__global__ __launch_bounds__(256) void k_csr(const int* __restrict__ pairs,
                                             const int* __restrict__ gcur,
                                             const float* __restrict__ x,
                                             int* __restrict__ starts2,
                                             int* __restrict__ srcs,
                                             float* __restrict__ dinv,
                                             __half2* __restrict__ xh,
                                             int* __restrict__ order,
                                             int n) {
  __shared__ int cnt[TILE];
  __shared__ int cur[TILE];
  __shared__ int sc[TILE];
  __shared__ float sdv[TILE];
  __shared__ int dh[64], dcur[64];
  int tid = threadIdx.x;
  int b = blockIdx.x;
  int tile0 = b * TILE;
  if (tid < TILE) cnt[tid] = 0;
  if (tid >= TILE && tid < TILE + 64) dh[tid - TILE] = 0;
  __syncthreads();
  int e0 = b * CAP, e1 = e0 + gcur[b];
  for (int i = e0 + tid; i < e1; i += 256)
    atomicAdd(&cnt[(unsigned)pairs[i] >> 20], 1);
  __syncthreads();
  int c = (tid < TILE) ? cnt[tid] : 0;
  if (tid < TILE) sc[tid] = c;
  __syncthreads();
  for (int off = 1; off < TILE; off <<= 1) {
    int t = (tid < TILE && tid >= off) ? sc[tid - off] : 0;
    __syncthreads();
    if (tid < TILE) sc[tid] += t;
    __syncthreads();
  }
  int mybin = 63;
  if (tid < TILE) {
    int excl = sc[tid] - c;
    cur[tid] = excl;
    int node = tile0 + tid;
    float d = rsqrtf(1.0f + (float)c);
    sdv[tid] = (node < n) ? d : 0.f;
    if (node < n) {
      starts2[node] = (e0 + excl) | (c << 22);
      dinv[node] = d;
      mybin = min(c, 62);  // valid nodes sort before invalid (bin 63)
    }
    atomicAdd(&dh[mybin], 1);
  }
  __syncthreads();
  if (tid == 0) {  // exclusive scan of 64 degree bins
    int a = 0;
    for (int i = 0; i < 64; ++i) { int t = dh[i]; dcur[i] = a; a += t; }
  }
  __syncthreads();
  if (tid < TILE) {
    int rank = atomicAdd(&dcur[mybin], 1);
    int node = tile0 + tid;
    order[tile0 + rank] = (node < n) ? node : SENT;
  }
  // edge placement (node-ordered within tile)
  for (int i = e0 + tid; i < e1; i += 256) {
    int p = pairs[i];
    int pos = atomicAdd(&cur[(unsigned)p >> 20], 1);
    srcs[e0 + pos] = p & 0xFFFFF;
  }
  // fused conversion: xs = dinv[node] * x (fp16)
  int nnode = min(n - tile0, TILE);
  if (nnode > 0) {
    int nfl = nnode * 16;  // float4 units
    const float4* xf = (const float4*)(x + (size_t)tile0 * 64);
    float2* xo = (float2*)xh + (size_t)tile0 * 16;
    for (int p = tid; p < nfl; p += 256) {
      float4 v = xf[p];
      float d = sdv[p >> 4];
      float2 st;
      ((__half2*)&st)[0] = __floats2half2_rn(v.x * d, v.y * d);
      ((__half2*)&st)[1] = __floats2half2_rn(v.z * d, v.w * d);
      xo[p] = st;
    }
  }
}

// --------- weighted accumulate: 8 halves of a float4-of-half2, w in {0,1} ------
__device__ __forceinline__ void acc8w(float2& a0, float2& a1, float2& a2,
                                      float2& a3, float4 v, float w) {
  const __half2* hp = (const __half2*)&v;
  float2 t;
  t = __half22float2(hp[0]); a0.x = fmaf(w, t.x, a0.x); a0.y = fmaf(w, t.y, a0.y);
  t = __half22float2(hp[1]); a1.x = fmaf(w, t.x, a1.x); a1.y = fmaf(w, t.y, a1.y);
  t = __half22float2(hp[2]); a2.x = fmaf(w, t.x, a2.x); a2.y = fmaf(w, t.y, a2.y);
  t = __half22float2(hp[3]); a3.x = fmaf(w, t.x, a3.x); a3.y = fmaf(w, t.y, a3.y);
}
__device__ __forceinline__ void acc8(float2& a0, float2& a1, float2& a2,
                                     float2& a3, float4 v) {
  const __half2* hp = (const __half2*)&v;
  float2 t;
  t = __half22float2(hp[0]); a0.x += t.x; a0.y += t.y;
  t = __half22float2(hp[1]); a1.x += t.x; a1.y += t.y;
  t = __half22float2(hp[2]); a2.x += t.x; a2.y += t.y;
  t = __half22float2(hp[3]); a3.x += t.x; a3.y += t.y;
}

// ------- gather1: z1s = dc^2*(xs_self + sum xs[srcs]); u-pool into Tr ----------
__global__ __launch_bounds__(256) void k_gather1(const int* __restrict__ starts2,
                                                 const int* __restrict__ srcs,
                                                 const float* __restrict__ dinv,
                                                 const __half2* __restrict__ xh,
                                                 const int* __restrict__ batch,
                                                 const int* __restrict__ order,
                                                 __half2* __restrict__ z1h,
                                                 float* __restrict__ Tr, int n) {
  int tid = threadIdx.x;
  int slot = blockIdx.x * 32 + (tid >> 3);
  int node = order[slot];
  bool act = node < n;
  int nc = act ? node : n - 1;
  int l = tid & 7;
  int lane = tid & 63;
  int rep = blockIdx.x & (NREP - 1);
  unsigned sv2 = (unsigned)starts2[nc];
  int s = sv2 & 0x3FFFFF;
  int deg = act ? (int)(sv2 >> 22) : 0;
  float dc = dinv[nc];
  int g = batch[nc];
  const float4* xf = (const float4*)xh;
  float4 sv = xf[(size_t)nc * 8 + l];
  float2 a0 = make_float2(0.f, 0.f), a1 = a0, a2 = a0, a3 = a0;
  acc8(a0, a1, a2, a3, sv);  // self term
  float wsum = 0.f;
  int trips = (deg + 3) >> 2;
  int dm1 = deg - 1;
  int r0 = 0, r1 = 0, r2 = 0, r3 = 0;
  if (trips > 0) {
    r0 = srcs[s];
    r1 = srcs[s + min(1, dm1)];
    r2 = srcs[s + min(2, dm1)];
    r3 = srcs[s + min(3, dm1)];
  }
  int j = 0;
  for (int t = 0; t < trips; ++t) {
    int n0 = r0, n1 = r1, n2 = r2, n3 = r3;
    int jn = j + 4;
    r0 = srcs[s + min(jn + 0, dm1)];
    r1 = srcs[s + min(jn + 1, dm1)];
    r2 = srcs[s + min(jn + 2, dm1)];
    r3 = srcs[s + min(jn + 3, dm1)];
    float w1w = (j + 1 < deg) ? 1.f : 0.f;
    float w2w = (j + 2 < deg) ? 1.f : 0.f;
    float w3w = (j + 3 < deg) ? 1.f : 0.f;
    float4 v0 = xf[(size_t)n0 * 8 + l];
    float4 v1 = xf[(size_t)n1 * 8 + l];
    float4 v2 = xf[(size_t)n2 * 8 + l];
    float4 v3 = xf[(size_t)n3 * 8 + l];
    wsum += dinv[n0] + w1w * dinv[n1] + w2w * dinv[n2] + w3w * dinv[n3];
    acc8(a0, a1, a2, a3, v0);
    acc8w(a0, a1, a2, a3, v1, w1w);
    acc8w(a0, a1, a2, a3, v2, w2w);
    acc8w(a0, a1, a2, a3, v3, w3w);
    j = jn;
  }
  if (act) {
    float s2 = dc * dc;
    float4 ov;
    __half2* op = (__half2*)&ov;
    op[0] = __floats2half2_rn(s2 * a0.x, s2 * a0.y);
    op[1] = __floats2half2_rn(s2 * a1.x, s2 * a1.y);
    op[2] = __floats2half2_rn(s2 * a2.x, s2 * a2.y);
    op[3] = __floats2half2_rn(s2 * a3.x, s2 * a3.y);
    ((float4*)z1h)[(size_t)node * 8 + l] = ov;
  }
  // pool u = dc*(dc+wsum) into T_rep (one atomic per wave in the common case)
  float uval = act ? dc * (dc + wsum) : 0.f;
  int g0 = __shfl(g, 0);
  bool uni = (__all(g == g0) != 0);
  if (!uni) {
    if (act && l == 0) unsafeAtomicAdd(&Tr[rep * NG + g], uval);
  } else {
    float uv = (l == 0) ? uval : 0.f;
    uv += __shfl_xor(uv, 8);
    uv += __shfl_xor(uv, 16);
    uv += __shfl_xor(uv, 32);
    if (lane == 0 && uv != 0.f) unsafeAtomicAdd(&Tr[rep * NG + g0], uv);
  }
}

// ------- gather2: row = dc*(z1s_self + sum z1s[srcs]); LDS-pool -> Pb partials --
__global__ __launch_bounds__(256) void k_gather2(const int* __restrict__ starts2,
                                                 const int* __restrict__ srcs,
                                                 const float* __restrict__ dinv,
                                                 const __half2* __restrict__ z1h,
                                                 const int* __restrict__ batch,
                                                 const int* __restrict__ order,
                                                 float* __restrict__ Pb,
                                                 float* __restrict__ S, int n) {
  __shared__ float rowacc[2][64];
  __shared__ int sgid[2];
  int tid = threadIdx.x;
  int blk0 = (int)blockIdx.x * 32;
  int slot = blk0 + (tid >> 3);
  int node = order[slot];
  bool act = node < n;
  int nc = act ? node : n - 1;
  int l = tid & 7;
  int lane = tid & 63;
  unsigned sv2 = (unsigned)starts2[nc];
  int s = sv2 & 0x3FFFFF;
  int deg = act ? (int)(sv2 >> 22) : 0;
  float dc = dinv[nc];
  int g = batch[nc];
  if (tid < 128) ((float*)rowacc)[tid] = 0.f;
  if (tid < 2) {
    int tile0b = blk0 & ~(TILE - 1);
    int idx = tile0b + (tid ? (TILE - 1) : 0);
    if (idx > n - 1) idx = n - 1;
    sgid[tid] = batch[idx];
  }
  const float4* xf = (const float4*)z1h;
  float4 sv = xf[(size_t)nc * 8 + l];
  float2 a0 = make_float2(0.f, 0.f), a1 = a0, a2 = a0, a3 = a0;
  acc8(a0, a1, a2, a3, sv);  // self term
  int trips = (deg + 3) >> 2;
  int dm1 = deg - 1;
  int r0 = 0, r1 = 0, r2 = 0, r3 = 0;
  if (trips > 0) {
    r0 = srcs[s];
    r1 = srcs[s + min(1, dm1)];
    r2 = srcs[s + min(2, dm1)];
    r3 = srcs[s + min(3, dm1)];
  }
  int j = 0;
  for (int t = 0; t < trips; ++t) {
    int n0 = r0, n1 = r1, n2 = r2, n3 = r3;
    int jn = j + 4;
    r0 = srcs[s + min(jn + 0, dm1)];
    r1 = srcs[s + min(jn + 1, dm1)];
    r2 = srcs[s + min(jn + 2, dm1)];
    r3 = srcs[s + min(jn + 3, dm1)];
    float w1w = (j + 1 < deg) ? 1.f : 0.f;
    float w2w = (j + 2 < deg) ? 1.f : 0.f;
    float w3w = (j + 3 < deg) ? 1.f : 0.f;
    float4 v0 = xf[(size_t)n0 * 8 + l];
    float4 v1 = xf[(size_t)n1 * 8 + l];
    float4 v2 = xf[(size_t)n2 * 8 + l];
    float4 v3 = xf[(size_t)n3 * 8 + l];
    acc8(a0, a1, a2, a3, v0);
    acc8w(a0, a1, a2, a3, v1, w1w);
    acc8w(a0, a1, a2, a3, v2, w2w);
    acc8w(a0, a1, a2, a3, v3, w3w);
    j = jn;
  }
  float f[8];
  f[0] = act ? dc * a0.x : 0.f;
  f[1] = act ? dc * a0.y : 0.f;
  f[2] = act ? dc * a1.x : 0.f;
  f[3] = act ? dc * a1.y : 0.f;
  f[4] = act ? dc * a2.x : 0.f;
  f[5] = act ? dc * a2.y : 0.f;
  f[6] = act ? dc * a3.x : 0.f;
  f[7] = act ? dc * a3.y : 0.f;
  __syncthreads();
  int g_lo = sgid[0], g_hi = sgid[1];
  int sel = (g == g_lo) ? 0 : ((g == g_hi) ? 1 : -1);
  if (sel < 0 && act) {  // >2 graphs in a 128-node tile: rare
#pragma unroll
    for (int k = 0; k < 8; ++k)
      unsafeAtomicAdd(&S[g * 64 + l * 8 + k], f[k]);
  }
  float fa[8], fb[8];
#pragma unroll
  for (int k = 0; k < 8; ++k) {
    fa[k] = (sel == 0) ? f[k] : 0.f;
    fb[k] = (sel == 1) ? f[k] : 0.f;
  }
#pragma unroll
  for (int k = 0; k < 8; ++k) {  // reduce over node dim (lane bits 3..5)
    fa[k] += __shfl_xor(fa[k], 8);
    fa[k] += __shfl_xor(fa[k], 16);
    fa[k] += __shfl_xor(fa[k], 32);
    fb[k] += __shfl_xor(fb[k], 8);
    fb[k] += __shfl_xor(fb[k], 16);
    fb[k] += __shfl_xor(fb[k], 32);
  }
  if (lane < 8) {
#pragma unroll
    for (int k = 0; k < 8; ++k) {
      if (fa[k] != 0.f) atomicAdd(&rowacc[0][lane * 8 + k], fa[k]);
      if (fb[k] != 0.f) atomicAdd(&rowacc[1][lane * 8 + k], fb[k]);
    }
  }
  __syncthreads();
  float* pb = Pb + (size_t)blockIdx.x * 130;
  if (tid < 128) pb[tid] = ((float*)rowacc)[tid];
  if (tid == 128) pb[128] = (float)g_lo;
  if (tid == 129) pb[129] = (float)g_hi;
}

// ------- fused: reduce Pb partials for graph g, then out[g] directly ------------
__global__ __launch_bounds__(256) void k_fin(const float* __restrict__ Pb,
                                             const int* __restrict__ batch,
                                             const float* __restrict__ S,
                                             const float* __restrict__ Tr,
                                             const float* __restrict__ cntf,
                                             const float* __restrict__ WW,
                                             const float* __restrict__ bw,
                                             const float* __restrict__ b2,
                                             float* __restrict__ out, int n,
                                             int nbw) {
  __shared__ float sh[4][64];
  __shared__ float sG[64];
  int g = blockIdx.x;
  int d = threadIdx.x & 63, r = threadIdx.x >> 6;
  int lo = 0, hi = n;
  while (lo < hi) { int m = (lo + hi) >> 1; if (batch[m] < g) lo = m + 1; else hi = m; }
  int a = lo;
  lo = 0; hi = n;
  while (lo < hi) { int m = (lo + hi) >> 1; if (batch[m] < g + 1) lo = m + 1; else hi = m; }
  int b = lo;
  float acc = 0.f;
  if (b > a) {
    // graph g's nodes live in tiles [a>>7, (b-1)>>7]; 4 gather blocks per tile
    int bl0 = (a >> 7) << 2;
    int bl1 = min((((b - 1) >> 7) << 2) + 3, nbw - 1);
    for (int bl = bl0 + r; bl <= bl1; bl += 4) {
      const float* p = Pb + (size_t)bl * 130;
      if ((int)p[128] == g) acc += p[d];
      if ((int)p[129] == g) acc += p[64 + d];
    }
  }
  sh[r][d] = acc;
  __syncthreads();
  if (r == 0) sG[d] = acc + sh[1][d] + sh[2][d] + sh[3][d] + S[g * 64 + d];
  __syncthreads();
  if (threadIdx.x < 64) {
    float aa = 0.f;
    for (int k = 0; k < 64; ++k) aa += sG[k] * WW[k * 64 + d];
    float T = 0.f;
    for (int rr = 0; rr < NREP; ++rr) T += Tr[rr * NG + g];
    float c = fmaxf(cntf[g], 1.0f);
    out[g * 64 + d] = (aa + T * bw[d]) / c + b2[d];
  }
}

extern "C" void kernel_launch(void* const* d_in, const int* in_sizes, int n_in,
                              void* d_out, int out_size, void* d_ws, size_t ws_size,
                              hipStream_t stream) {
  const float* x = (const float*)d_in[0];
  const int* ei = (const int*)d_in[1];
  const int* bat = (const int*)d_in[2];
  const float* W1 = (const float*)d_in[3];
  const float* b1 = (const float*)d_in[4];
  const float* W2 = (const float*)d_in[5];
  const float* b2 = (const float*)d_in[6];
  float* out = (float*)d_out;

  int n = in_sizes[0] / 64;  // 100000
  int e = in_sizes[1] / 2;   // 1000000
  const int* rowp = ei;      // sources
  const int* colp = ei + e;  // targets
  int nb = (n + TILE - 1) / TILE;                  // 782 buckets (< NBMAX)
  int chunk = (((e + NBLK - 1) / NBLK) + 3) & ~3;  // 4-aligned for int4 reads
  int nbw = (n + 31) / 32;                         // gather blocks: 32 slots each

  char* ws = (char*)d_ws;
  size_t off = 0;
  auto alloc = [&](size_t elems) {
    void* p = ws + off;
    off += ((elems * 4 + 255) & ~(size_t)255);
    return p;
  };
  // zeroed prefix: S, Tr, cntf, gcur
  float* S = (float*)alloc(NG * DFEAT);
  float* Tr = (float*)alloc(NREP * NG);
  float* cntf = (float*)alloc(NG);
  int* gcur = (int*)alloc(nb);
  size_t zbytes = off;
  float* dinv = (float*)alloc(n);
  int* starts2 = (int*)alloc(n);
  int* srcs = (int*)alloc((size_t)nb * CAP);
  float* WW = (float*)alloc(DFEAT * DFEAT);
  float* bw = (float*)alloc(DFEAT);
  __half2* xh = (__half2*)alloc((size_t)n * 32);   // n*64 halves (premultiplied)
  __half2* z1h = (__half2*)alloc((size_t)n * 32);  // n*64 halves (z1s)
  int* pairs = (int*)alloc((size_t)nb * CAP);
  float* Pb = (float*)alloc((size_t)nbw * 130);    // per-block pooled partials
  int* order = (int*)alloc((size_t)nb * TILE);     // degree-sorted slot->node

  (void)hipMemsetAsync(S, 0, zbytes, stream);
  // fused: histogram + bucket-region reservation + placement (+W12 in block 256)
  k_binfuse<<<NBLK + 1, 256, 0, stream>>>(rowp, colp, gcur, pairs, W1, W2, b1,
                                          bat, WW, bw, cntf, e, nb, chunk, n);
  k_csr<<<nb, 256, 0, stream>>>(pairs, gcur, x, starts2, srcs, dinv, xh, order,
                                n);

  // layer 1: z1s = dinv^2*(xs_self + sum xs) (+ fused u-pool into Tr)
  // layer 2: pooled rows -> per-block partials Pb (+ rare fallback atomics to S)
  k_gather1<<<nbw, 256, 0, stream>>>(starts2, srcs, dinv, xh, bat, order, z1h,
                                     Tr, n);
  k_gather2<<<nbw, 256, 0, stream>>>(starts2, srcs, dinv, z1h, bat, order, Pb,
                                     S, n);

  // fused partial-reduce + tiny matmul + bias
  k_fin<<<NG, 256, 0, stream>>>(Pb, bat, S, Tr, cntf, WW, bw, b2, out, n, nbw);
}